// Round 12
// baseline (102.065 us; speedup 1.0000x reference)
//
#include <hip/hip_runtime.h>
#include <math.h>

// R17: R16 base (proven 49.0us, VALUBusy 82%) + MAXIMAL RCP-BATCHING.
// Slot model calibrated from measured busy: wave64 v_exp/v_rcp occupy the
// issue port ~16cy (quarter-rate) -> trans ops are ~55% of all issue. R16's
// paired-rcp win confirmed the model. This round: Montgomery batching --
// one rcp + prefix/suffix products serves N reciprocals.
//  - ph1: 4 rcp -> 1 rcp + ~14 VALU (-32 cy/iter)
//  - ph3: 3 rcp -> 1 rcp + ~8 VALU  (-18 cy/iter)
//  - ph2: speculative-opn rcp paired with den rcp: 2 -> 1 (-8 cy/iter)
// Safety: all e clamped to 1e9 BEFORE q=1+e (P<=1e36 finite; sigma<1e-9 == 0
// at f32, and 1-1e-9 rounds to 1.0f -> T-chain identical). Without clamps a
// single inf channel would NaN-poison the batch. Precision ~4e-7 relative
// (vs 1.2e-7 solo) -- 4 orders under tolerance, same class as R9/R13.
// Retained: INF-sentinel merge, off-chain mult-form chains, speculative opn,
// depth-2 ds prefetch, u-increment, per-block minmax (no memset).
// LDS fd[66][64] = 16.9KB -> 8 blocks/CU = 2 waves/SIMD.

#define NT 64
#define PTS 64
#define NRAYS (2*256*256)
#define NEARV 0.1f
#define STEPV (1.9f/63.0f)
#define FAR63 (0.1f + 63.0f*(1.9f/63.0f))
#define NL2E (-1.4426950408889634f)
#define ECL9 1.0e9f
#define BIGF 3.0e38f

__global__ __launch_bounds__(NT, 2) void nerf_main(
    const float* __restrict__ tm, const float* __restrict__ wq,
    float* __restrict__ out, unsigned int* __restrict__ bmm)
{
    __shared__ float fd[PTS + 2][NT];      // rows 0..63 fine depths, 64 = +INF
    const int tid = threadIdx.x;           // sentinel, 65 = junk dump row
    const int r = blockIdx.x * NT + tid;
    const int b = r >> 16, n = r & 65535;
    const int i = n >> 8, j = n & 255;

    float bA[4], sA[4];                    // feat[c]*(-log2e) = bA + d*sA
    {
        float cx = (1.0f + (float)j * (-2.0f/255.0f)) * (1.0f/4.2f);
        float cy = (1.0f + (float)i * (-2.0f/255.0f)) * (1.0f/4.2f);
        const float* tmb = tm + b*12;
        float dx = tmb[0]*cx + tmb[1]*cy + tmb[2];
        float dy = tmb[4]*cx + tmb[5]*cy + tmb[6];
        float dz = tmb[8]*cx + tmb[9]*cy + tmb[10];
        float ox = tmb[3], oy = tmb[7], oz = tmb[11];
        #pragma unroll
        for (int c = 0; c < 4; c++) {
            float s  = dx*wq[0*4+c] + dy*wq[1*4+c] + dz*wq[2*4+c];
            float bv = ox*wq[0*4+c] + oy*wq[1*4+c] + oz*wq[2*4+c]
                     + dx*wq[3*4+c] + dy*wq[4*4+c] + dz*wq[5*4+c];
            sA[c] = s * NL2E;
            bA[c] = bv * NL2E;
        }
    }

    // recurrence state: eV[c] = exp2(bA + d*sA) at the current coarse point,
    // kV[c] = per-step ratio exp2(sA*STEP). e00 = eV[0] at d = NEAR.
    float eV[4], kV[4], e00;
    #pragma unroll
    for (int c = 0; c < 4; c++) {
        eV[c] = __builtin_amdgcn_exp2f(bA[c] + NEARV*sA[c]);
        kV[c] = __builtin_amdgcn_exp2f(sA[c]*STEPV);
    }
    e00 = eV[0];

    // ---- phase 1: coarse march, zero exp2, batched rcp (4 -> 1) ----
    float T = 1.0f, S = 0.0f;
    float a0 = 0.0f, a1 = 0.0f, a2 = 0.0f;
    #pragma unroll 4
    for (int p = 0; p < PTS; p++) {
        float e0c = fminf(eV[0], ECL9);
        float q0 = 1.0f + e0c;
        float q1 = 1.0f + fminf(eV[1], ECL9);
        float q2 = 1.0f + fminf(eV[2], ECL9);
        float q3 = 1.0f + fminf(eV[3], ECL9);
        float p01 = q0 * q1, p23 = q2 * q3;
        float R = __builtin_amdgcn_rcpf(p01 * p23);    // ONE rcp, four sigmoids
        float i01 = R * p23, i23 = R * p01;
        float r0 = i01 * q1;                           // 1/q0 = op
        float v0 = i01 * q0;                           // 1/q1
        float v1 = i23 * q3;                           // 1/q2
        float v2 = i23 * q2;                           // 1/q3
        float m0 = e0c * r0;                           // 1-op, off-chain
        eV[0] *= kV[0];
        eV[1] *= kV[1];
        eV[2] *= kV[2];
        eV[3] *= kV[3];
        float w = r0 * T;
        a0 = fmaf(w, v0, a0);
        a1 = fmaf(w, v1, a1);
        a2 = fmaf(w, v2, a2);
        S += w;
        T *= m0;                                       // chain: one v_mul
    }
    S += 64.0f * 1e-5f;                                // hoisted pad sum
    out[(b*3+0)*65536 + n] = a0;
    out[(b*3+1)*65536 + n] = a1;
    out[(b*3+2)*65536 + n] = a2;

    fd[PTS][tid] = BIGF;                               // +INF sentinel row

    // ---- phase 2: sampling machine; opn-rcp paired with den-rcp (2 -> 1) --
    float Sinv = __builtin_amdgcn_rcpf(S);
    float op0  = __builtin_amdgcn_rcpf(1.0f + e00);    // sigmoid at d = NEAR
    float T2   = 1.0f - op0;
    float c_lo = 0.0f;
    float c_hi = (op0 + 1e-5f) * Sinv;                 // cdf[0]
    int ind = 0, wslot = 0;
    float u = 0.015625f;                               // k/64, exact increments
    float bin_prev = NEARV;                            // bin_0 == NEAR always
    float eP  = e00 * kV[0];                           // index m = 1
    float opn = __builtin_amdgcn_rcpf(1.0f + eP);
    #pragma unroll 2
    for (int it = 0; it < 2*PTS; it++) {
        float eP2 = eP * kV[0];                        // speculative advance
        float qA  = 1.0f + fminf(eP2, 1.0e18f);        // clamp: P finite
        bool adv = (ind < PTS) && (c_hi <= u);         // searchsorted 'right'
        float wn  = opn * T2;
        float d0  = fmaf((float)(ind - 1), STEPV, NEARV);
        float den = c_hi - c_lo;
        den = (den < 1e-8f) ? 1.0f : den;              // ref guard
        float P2 = qA * den;
        float R2 = __builtin_amdgcn_rcpf(P2);          // ONE rcp: opnB + 1/den
        float opnB = R2 * den;                         // ~1/qA (next-iter opn)
        float t = (u - c_lo) * (R2 * qA);              // (u-c_lo)/den
        t = fminf(fmaxf(t, 0.0f), 1.0f);
        float bin = fmaf(t, STEPV, d0);
        bin = (ind <= 0)   ? NEARV : bin;
        bin = (ind >= PTS) ? FAR63 : bin;
        float fdep = 0.5f * (bin_prev + bin);
        // emits are provably <=64 (wslot<64); defensive: overflow -> row 65
        int widx = adv ? (PTS + 1) : ((wslot < PTS) ? wslot : (PTS + 1));
        fd[widx][tid] = fdep;                          // unconditional ds_write
        float nc_hi = c_hi + (wn + 1e-5f) * Sinv;
        float nT2   = T2 * (1.0f - opn);
        bool advm   = adv && (ind < 62);               // m=min(ind+1,63) moves
        c_lo     = adv ? c_hi : c_lo;
        c_hi     = adv ? nc_hi : c_hi;
        T2       = adv ? nT2 : T2;
        bin_prev = adv ? bin_prev : bin;
        eP  = advm ? eP2  : eP;
        opn = advm ? opnB : opn;                       // select, not recompute
        ind += adv ? 1 : 0;
        u  += adv ? 0.0f : 0.015625f;                  // exact k/64 increments
        wslot += adv ? 0 : 1;                          // plain inc (guard in widx)
    }

    // ---- phase 3: merge, INF-sentinel compare, batched rcp (3 -> 1) ----
    const float bA0 = bA[0], sA0 = sA[0], bA1 = bA[1], sA1 = sA[1];
    const float bA2 = bA[2], sA2 = sA[2], bA3 = bA[3], sA3 = sA[3];
    float T3 = 1.0f, sw = 0.0f, rd = 0.0f;
    float f0 = 0.0f, f1 = 0.0f, f2 = 0.0f;
    int pc = 0, pf = 0;
    float dc = NEARV;
    float cur = fd[0][tid], nxt = fd[1][tid];
    float tmp = fd[2][tid];                            // in-flight prefetch
    #pragma unroll 4
    for (int it = 0; it < 2*PTS; it++) {
        float pend = tmp;                              // completed ~1 iter ago
        bool tc = (dc <= cur);                         // ties -> coarse; INF
        float d = tc ? dc : cur;                       //   sentinel ends fine
        pc += tc ? 1 : 0;
        dc = fmaf((float)pc, STEPV, NEARV);
        cur = tc ? cur : nxt;
        nxt = tc ? nxt : pend;                         // pend == fd[pf_old+2]
        pf += tc ? 0 : 1;
        tmp = fd[min(pf + 2, PTS)][tid];               // issue for next iter
        float e0 = __builtin_amdgcn_exp2f(fmaf(d, sA0, bA0));
        float e1 = __builtin_amdgcn_exp2f(fmaf(d, sA1, bA1));
        float e2 = __builtin_amdgcn_exp2f(fmaf(d, sA2, bA2));
        float e3 = __builtin_amdgcn_exp2f(fmaf(d, sA3, bA3));
        float e0c = fminf(e0, ECL9);
        float q0 = 1.0f + e0c;
        float q1 = 1.0f + fminf(e1, ECL9);
        float q2 = 1.0f + fminf(e2, ECL9);
        float q3 = 1.0f + fminf(e3, ECL9);
        float p01 = q0 * q1, p23 = q2 * q3;
        float R = __builtin_amdgcn_rcpf(p01 * p23);    // ONE rcp, four sigmoids
        float i01 = R * p23, i23 = R * p01;
        float r0 = i01 * q1;                           // op
        float v0 = i01 * q0;
        float v1 = i23 * q3;
        float v2 = i23 * q2;
        float m0 = e0c * r0;                           // 1-op, off-chain
        float w = r0 * T3;
        f0 = fmaf(w, v0, f0);
        f1 = fmaf(w, v1, f1);
        f2 = fmaf(w, v2, f2);
        sw += w;
        rd  = fmaf(w, d, rd);
        T3 *= m0;                                      // chain: one v_mul
    }

    out[393216 + (b*3+0)*65536 + n] = f0;
    out[393216 + (b*3+1)*65536 + n] = f1;
    out[393216 + (b*3+2)*65536 + n] = f2;
    float fop  = fminf(fmaxf(sw, 0.0f), 1.0f);
    float rdep = rd + (1.0f - fop) * 2.0f;             // d_all.max() == 2.0 exactly
    out[786432 + r] = rdep;

    unsigned ub  = __float_as_uint(rdep);              // rdep>0: u32 order == float order
    unsigned kmn = ub;
    unsigned kmx = ~ub;
    #pragma unroll
    for (int m = 32; m >= 1; m >>= 1) {
        unsigned omn = (unsigned)__shfl_xor((int)kmn, m, 64);
        unsigned omx = (unsigned)__shfl_xor((int)kmx, m, 64);
        kmn = (omn < kmn) ? omn : kmn;
        kmx = (omx < kmx) ? omx : kmx;
    }
    if (tid == 0) {
        bmm[2*blockIdx.x + 0] = kmn;                   // plain stores: no init,
        bmm[2*blockIdx.x + 1] = kmx;                   // no atomics, replay-safe
    }
}

__global__ __launch_bounds__(256) void nerf_norm(float* __restrict__ out,
                                                 const unsigned int* __restrict__ bmm)
{
    const int tid = threadIdx.x;
    // reduce 2048 per-block pairs (16KB, L2-resident broadcast)
    unsigned kmn = 0xFFFFFFFFu, kmx = 0xFFFFFFFFu;
    const uint2* bm2 = (const uint2*)bmm;
    #pragma unroll
    for (int t = 0; t < 8; t++) {
        uint2 p = bm2[tid + 256*t];
        kmn = min(kmn, p.x);
        kmx = min(kmx, p.y);
    }
    #pragma unroll
    for (int m = 32; m >= 1; m >>= 1) {
        unsigned omn = (unsigned)__shfl_xor((int)kmn, m, 64);
        unsigned omx = (unsigned)__shfl_xor((int)kmx, m, 64);
        kmn = (omn < kmn) ? omn : kmn;
        kmx = (omx < kmx) ? omx : kmx;
    }
    __shared__ unsigned smn[4], smx[4];
    if ((tid & 63) == 0) { smn[tid >> 6] = kmn; smx[tid >> 6] = kmx; }
    __syncthreads();
    kmn = min(min(smn[0], smn[1]), min(smn[2], smn[3]));
    kmx = min(min(smx[0], smx[1]), min(smx[2], smx[3]));
    float mn = __uint_as_float(kmn);
    float mx = __uint_as_float(~kmx);
    int idx = blockIdx.x * 256 + tid;
    float v = out[786432 + idx];
    out[786432 + idx] = (v - mn) * __builtin_amdgcn_rcpf(mx - mn);
}

extern "C" void kernel_launch(void* const* d_in, const int* in_sizes, int n_in,
                              void* d_out, int out_size, void* d_ws, size_t ws_size,
                              hipStream_t stream) {
    (void)in_sizes; (void)n_in; (void)out_size; (void)ws_size;
    const float* tm = (const float*)d_in[0];
    const float* wq = (const float*)d_in[1];
    float* out = (float*)d_out;
    unsigned int* bmm = (unsigned int*)d_ws;           // 2048 pairs = 16KB
    nerf_main<<<NRAYS/NT, NT, 0, stream>>>(tm, wq, out, bmm);
    nerf_norm<<<NRAYS/256, 256, 0, stream>>>(out, bmm);
}

// Round 13
// 100.844 us; speedup vs baseline: 1.0121x; 1.0121x over previous
//
#include <hip/hip_runtime.h>
#include <math.h>

// R18 = R16 REVERT (proven 49.0us main / 100.7us total, VALUBusy 82%).
// R17 (maximal rcp-batching) regressed to 55.1us and falsified the 16-cy
// trans model: v_rcp issue cost ~ a couple VALU ops, and batching's serial
// mul->rcp->mul tree added unhidable latency (2 streams/SIMD). Reverting
// verbatim; if this reproduces ~49us the kernel is at its practical
// roofline: VALU-issue-bound (82%), HBM 0.96%, occupancy proven irrelevant
// (R0~R3, R15 regression), chain-stalls removed (R6/R14b/R16), remaining
// ~18% stall unreachable with 2 wave-streams/SIMD.
// Structure: INF pad row (guard-free merge compare), paired rcp for (e1,e2)
// in ph3 only, off-chain mult-form T-chains, speculative opn in ph2, depth-2
// ds prefetch, u-increment, per-block minmax stores (no memset/no atomics).
// LDS fd[66][64]=16.9KB -> 8 blocks/CU = 2 waves/SIMD.

#define NT 64
#define PTS 64
#define NRAYS (2*256*256)
#define NEARV 0.1f
#define STEPV (1.9f/63.0f)
#define FAR63 (0.1f + 63.0f*(1.9f/63.0f))
#define NL2E (-1.4426950408889634f)
#define ECLAMP 1.0e37f
#define ECLAMP2 1.0e18f
#define BIGF 3.0e38f

__global__ __launch_bounds__(NT, 2) void nerf_main(
    const float* __restrict__ tm, const float* __restrict__ wq,
    float* __restrict__ out, unsigned int* __restrict__ bmm)
{
    __shared__ float fd[PTS + 2][NT];      // rows 0..63 fine depths, 64 = +INF
    const int tid = threadIdx.x;           // sentinel, 65 = junk dump row
    const int r = blockIdx.x * NT + tid;
    const int b = r >> 16, n = r & 65535;
    const int i = n >> 8, j = n & 255;

    float bA[4], sA[4];                    // feat[c]*(-log2e) = bA + d*sA
    {
        float cx = (1.0f + (float)j * (-2.0f/255.0f)) * (1.0f/4.2f);
        float cy = (1.0f + (float)i * (-2.0f/255.0f)) * (1.0f/4.2f);
        const float* tmb = tm + b*12;
        float dx = tmb[0]*cx + tmb[1]*cy + tmb[2];
        float dy = tmb[4]*cx + tmb[5]*cy + tmb[6];
        float dz = tmb[8]*cx + tmb[9]*cy + tmb[10];
        float ox = tmb[3], oy = tmb[7], oz = tmb[11];
        #pragma unroll
        for (int c = 0; c < 4; c++) {
            float s  = dx*wq[0*4+c] + dy*wq[1*4+c] + dz*wq[2*4+c];
            float bv = ox*wq[0*4+c] + oy*wq[1*4+c] + oz*wq[2*4+c]
                     + dx*wq[3*4+c] + dy*wq[4*4+c] + dz*wq[5*4+c];
            sA[c] = s * NL2E;
            bA[c] = bv * NL2E;
        }
    }

    // recurrence state: eV[c] = exp2(bA + d*sA) at the current coarse point,
    // kV[c] = per-step ratio exp2(sA*STEP). e00 = eV[0] at d = NEAR.
    float eV[4], kV[4], e00;
    #pragma unroll
    for (int c = 0; c < 4; c++) {
        eV[c] = __builtin_amdgcn_exp2f(bA[c] + NEARV*sA[c]);
        kV[c] = __builtin_amdgcn_exp2f(sA[c]*STEPV);
    }
    e00 = eV[0];

    // ---- phase 1: coarse march, zero exp2, 1-mul carried chain ----
    float T = 1.0f, S = 0.0f;
    float a0 = 0.0f, a1 = 0.0f, a2 = 0.0f;
    #pragma unroll 4
    for (int p = 0; p < PTS; p++) {
        float e0c = fminf(eV[0], ECLAMP);
        float r0 = __builtin_amdgcn_rcpf(1.0f + e0c);  // op
        float m0 = e0c * r0;                           // 1-op, off-chain
        float v0 = __builtin_amdgcn_rcpf(1.0f + eV[1]);
        float v1 = __builtin_amdgcn_rcpf(1.0f + eV[2]);
        float v2 = __builtin_amdgcn_rcpf(1.0f + eV[3]);
        eV[0] *= kV[0];
        eV[1] *= kV[1];
        eV[2] *= kV[2];
        eV[3] *= kV[3];
        float w = r0 * T;
        a0 = fmaf(w, v0, a0);
        a1 = fmaf(w, v1, a1);
        a2 = fmaf(w, v2, a2);
        S += w;
        T *= m0;                                       // chain: one v_mul
    }
    S += 64.0f * 1e-5f;                                // hoisted pad sum
    out[(b*3+0)*65536 + n] = a0;
    out[(b*3+1)*65536 + n] = a1;
    out[(b*3+2)*65536 + n] = a2;

    fd[PTS][tid] = BIGF;                               // +INF sentinel row

    // ---- phase 2: branchless sampling machine, zero exp2, speculative opn --
    float Sinv = __builtin_amdgcn_rcpf(S);
    float op0  = __builtin_amdgcn_rcpf(1.0f + e00);    // sigmoid at d = NEAR
    float T2   = 1.0f - op0;
    float c_lo = 0.0f;
    float c_hi = (op0 + 1e-5f) * Sinv;                 // cdf[0]
    int ind = 0, wslot = 0;
    float u = 0.015625f;                               // k/64, exact increments
    float bin_prev = NEARV;                            // bin_0 == NEAR always
    float eP  = e00 * kV[0];                           // index m = 1
    float opn = __builtin_amdgcn_rcpf(1.0f + eP);
    #pragma unroll 2
    for (int it = 0; it < 2*PTS; it++) {
        float eP2  = eP * kV[0];                       // speculative advance
        float opnB = __builtin_amdgcn_rcpf(1.0f + eP2);// off-chain rcp
        bool adv = (ind < PTS) && (c_hi <= u);         // searchsorted 'right'
        float wn  = opn * T2;
        float d0  = fmaf((float)(ind - 1), STEPV, NEARV);
        float den = c_hi - c_lo;
        den = (den < 1e-8f) ? 1.0f : den;              // ref guard
        float t = (u - c_lo) * __builtin_amdgcn_rcpf(den);
        t = fminf(fmaxf(t, 0.0f), 1.0f);
        float bin = fmaf(t, STEPV, d0);
        bin = (ind <= 0)   ? NEARV : bin;
        bin = (ind >= PTS) ? FAR63 : bin;
        float fdep = 0.5f * (bin_prev + bin);
        // emits are provably <=64 (wslot<64); defensive: overflow -> row 65
        int widx = adv ? (PTS + 1) : ((wslot < PTS) ? wslot : (PTS + 1));
        fd[widx][tid] = fdep;                          // unconditional ds_write
        float nc_hi = c_hi + (wn + 1e-5f) * Sinv;
        float nT2   = T2 * (1.0f - opn);
        bool advm   = adv && (ind < 62);               // m=min(ind+1,63) moves
        c_lo     = adv ? c_hi : c_lo;
        c_hi     = adv ? nc_hi : c_hi;
        T2       = adv ? nT2 : T2;
        bin_prev = adv ? bin_prev : bin;
        eP  = advm ? eP2  : eP;
        opn = advm ? opnB : opn;                       // select, not recompute
        ind += adv ? 1 : 0;
        u  += adv ? 0.0f : 0.015625f;                  // exact k/64 increments
        wslot += adv ? 0 : 1;                          // plain inc (guard in widx)
    }

    // ---- phase 3: merge, INF-sentinel (guard-free compare), paired rcp ----
    const float bA0 = bA[0], sA0 = sA[0], bA1 = bA[1], sA1 = sA[1];
    const float bA2 = bA[2], sA2 = sA[2], bA3 = bA[3], sA3 = sA[3];
    float T3 = 1.0f, sw = 0.0f, rd = 0.0f;
    float f0 = 0.0f, f1 = 0.0f, f2 = 0.0f;
    int pc = 0, pf = 0;
    float dc = NEARV;
    float cur = fd[0][tid], nxt = fd[1][tid];
    float tmp = fd[2][tid];                            // in-flight prefetch
    #pragma unroll 4
    for (int it = 0; it < 2*PTS; it++) {
        float pend = tmp;                              // completed ~1 iter ago
        bool tc = (dc <= cur);                         // ties -> coarse; INF
        float d = tc ? dc : cur;                       //   sentinel ends fine
        pc += tc ? 1 : 0;
        dc = fmaf((float)pc, STEPV, NEARV);
        cur = tc ? cur : nxt;
        nxt = tc ? nxt : pend;                         // pend == fd[pf_old+2]
        pf += tc ? 0 : 1;
        tmp = fd[min(pf + 2, PTS)][tid];               // issue for next iter
        float e0 = __builtin_amdgcn_exp2f(fmaf(d, sA0, bA0));
        float e1 = __builtin_amdgcn_exp2f(fmaf(d, sA1, bA1));
        float e2 = __builtin_amdgcn_exp2f(fmaf(d, sA2, bA2));
        float e3 = __builtin_amdgcn_exp2f(fmaf(d, sA3, bA3));
        float e0c = fminf(e0, ECLAMP);
        float r0 = __builtin_amdgcn_rcpf(1.0f + e0c);  // op
        float m0 = e0c * r0;                           // 1-op, off-chain
        float e1c = fminf(e1, ECLAMP2);                // clamp so q1*q2 finite
        float e2c = fminf(e2, ECLAMP2);
        float q1 = 1.0f + e1c, q2 = 1.0f + e2c;
        float r12 = __builtin_amdgcn_rcpf(q1 * q2);    // one rcp, two sigmoids
        float v0 = r12 * q2;
        float v1 = r12 * q1;
        float v2 = __builtin_amdgcn_rcpf(1.0f + e3);
        float w = r0 * T3;
        f0 = fmaf(w, v0, f0);
        f1 = fmaf(w, v1, f1);
        f2 = fmaf(w, v2, f2);
        sw += w;
        rd  = fmaf(w, d, rd);
        T3 *= m0;                                      // chain: one v_mul
    }

    out[393216 + (b*3+0)*65536 + n] = f0;
    out[393216 + (b*3+1)*65536 + n] = f1;
    out[393216 + (b*3+2)*65536 + n] = f2;
    float fop  = fminf(fmaxf(sw, 0.0f), 1.0f);
    float rdep = rd + (1.0f - fop) * 2.0f;             // d_all.max() == 2.0 exactly
    out[786432 + r] = rdep;

    unsigned ub  = __float_as_uint(rdep);              // rdep>0: u32 order == float order
    unsigned kmn = ub;
    unsigned kmx = ~ub;
    #pragma unroll
    for (int m = 32; m >= 1; m >>= 1) {
        unsigned omn = (unsigned)__shfl_xor((int)kmn, m, 64);
        unsigned omx = (unsigned)__shfl_xor((int)kmx, m, 64);
        kmn = (omn < kmn) ? omn : kmn;
        kmx = (omx < kmx) ? omx : kmx;
    }
    if (tid == 0) {
        bmm[2*blockIdx.x + 0] = kmn;                   // plain stores: no init,
        bmm[2*blockIdx.x + 1] = kmx;                   // no atomics, replay-safe
    }
}

__global__ __launch_bounds__(256) void nerf_norm(float* __restrict__ out,
                                                 const unsigned int* __restrict__ bmm)
{
    const int tid = threadIdx.x;
    // reduce 2048 per-block pairs (16KB, L2-resident broadcast)
    unsigned kmn = 0xFFFFFFFFu, kmx = 0xFFFFFFFFu;
    const uint2* bm2 = (const uint2*)bmm;
    #pragma unroll
    for (int t = 0; t < 8; t++) {
        uint2 p = bm2[tid + 256*t];
        kmn = min(kmn, p.x);
        kmx = min(kmx, p.y);
    }
    #pragma unroll
    for (int m = 32; m >= 1; m >>= 1) {
        unsigned omn = (unsigned)__shfl_xor((int)kmn, m, 64);
        unsigned omx = (unsigned)__shfl_xor((int)kmx, m, 64);
        kmn = (omn < kmn) ? omn : kmn;
        kmx = (omx < kmx) ? omx : kmx;
    }
    __shared__ unsigned smn[4], smx[4];
    if ((tid & 63) == 0) { smn[tid >> 6] = kmn; smx[tid >> 6] = kmx; }
    __syncthreads();
    kmn = min(min(smn[0], smn[1]), min(smn[2], smn[3]));
    kmx = min(min(smx[0], smx[1]), min(smx[2], smx[3]));
    float mn = __uint_as_float(kmn);
    float mx = __uint_as_float(~kmx);
    int idx = blockIdx.x * 256 + tid;
    float v = out[786432 + idx];
    out[786432 + idx] = (v - mn) * __builtin_amdgcn_rcpf(mx - mn);
}

extern "C" void kernel_launch(void* const* d_in, const int* in_sizes, int n_in,
                              void* d_out, int out_size, void* d_ws, size_t ws_size,
                              hipStream_t stream) {
    (void)in_sizes; (void)n_in; (void)out_size; (void)ws_size;
    const float* tm = (const float*)d_in[0];
    const float* wq = (const float*)d_in[1];
    float* out = (float*)d_out;
    unsigned int* bmm = (unsigned int*)d_ws;           // 2048 pairs = 16KB
    nerf_main<<<NRAYS/NT, NT, 0, stream>>>(tm, wq, out, bmm);
    nerf_norm<<<NRAYS/256, 256, 0, stream>>>(out, bmm);
}